// Round 3
// baseline (1018.396 us; speedup 1.0000x reference)
//
#include <hip/hip_runtime.h>
#include <cstdint>
#include <cfloat>
#include <cmath>

// Problem constants (from reference)
#define B_    32
#define M_    16384
#define WC    256
#define R_    8
#define K_    16
#define KL_   16
#define IN_   1024
#define TKL_  32
#define C_    161        // R*K + TKL + 1
#define NOUT  2466       // 2048 + 256 + 161 + 1

// ---------------------------------------------------------------------------
// Kernel A: fused small GEMMs  y = x @ W.T + b  for W_rq / W_wv / W_ig / W_wg
// Tiled: 16 output rows per block, all 32 batches, k-chunks of 256.
// NOTE (audited, deferred): DS-bound (~15us, 3 ds_read_b128 per 8 MACs).
// Rewrite to no-LDS wave-tile (scores_kernel pattern) once baseline passes.
// ---------------------------------------------------------------------------
__global__ __launch_bounds__(256) void gemm_small(
    const float* __restrict__ x,
    const float* __restrict__ W_rq, const float* __restrict__ b_rq,
    const float* __restrict__ W_wv, const float* __restrict__ b_wv,
    const float* __restrict__ W_ig, const float* __restrict__ b_ig,
    const float* __restrict__ W_wg, const float* __restrict__ b_wg,
    float* __restrict__ rq_buf, float* __restrict__ wv_buf,
    float* __restrict__ gate_buf, float* __restrict__ wg_buf)
{
  const int tid = threadIdx.x;
  const int n0  = blockIdx.x * 16;
  __shared__ float Wl[16 * 260];
  __shared__ float Xl[32 * 260];
  const int b   = tid & 31;
  const int ns0 = tid >> 5;          // 0..7
  float acc0 = 0.f, acc1 = 0.f;

  for (int kc = 0; kc < 4; ++kc) {
    __syncthreads();
    // load W tile: 16 rows x 256 cols
    #pragma unroll
    for (int t = 0; t < 4; ++t) {
      const int q = t * 256 + tid;
      const int row = q >> 6, col4 = q & 63;
      const int gn = n0 + row;
      float4 v = make_float4(0.f, 0.f, 0.f, 0.f);
      if (gn < NOUT) {
        const float* wp; int rr;
        if (gn < 2048)       { wp = W_rq; rr = gn; }
        else if (gn < 2304)  { wp = W_wv; rr = gn - 2048; }
        else if (gn < 2465)  { wp = W_ig; rr = gn - 2304; }
        else                 { wp = W_wg; rr = 0; }
        v = *(const float4*)(wp + (size_t)rr * IN_ + kc * 256 + col4 * 4);
      }
      *(float4*)(Wl + row * 260 + col4 * 4) = v;
    }
    // load x tile: 32 batches x 256 cols
    #pragma unroll
    for (int t = 0; t < 8; ++t) {
      const int q = t * 256 + tid;
      const int bb = q >> 6, col4 = q & 63;
      *(float4*)(Xl + bb * 260 + col4 * 4) =
          *(const float4*)(x + (size_t)bb * IN_ + kc * 256 + col4 * 4);
    }
    __syncthreads();
    #pragma unroll 8
    for (int j4 = 0; j4 < 64; ++j4) {
      const float4 xv = *(const float4*)(Xl + b * 260 + j4 * 4);
      const float4 w0 = *(const float4*)(Wl + ns0 * 260 + j4 * 4);
      const float4 w1 = *(const float4*)(Wl + (ns0 + 8) * 260 + j4 * 4);
      acc0 += xv.x * w0.x + xv.y * w0.y + xv.z * w0.z + xv.w * w0.w;
      acc1 += xv.x * w1.x + xv.y * w1.y + xv.z * w1.z + xv.w * w1.w;
    }
  }

  // epilogue: route the two outputs
  #pragma unroll
  for (int h = 0; h < 2; ++h) {
    const int gn = n0 + ns0 + h * 8;
    const float dot = h ? acc1 : acc0;
    if (gn < NOUT) {
      if (gn < 2048)      rq_buf[b * 2048 + gn] = dot + b_rq[gn];
      else if (gn < 2304) wv_buf[b * WC + (gn - 2048)] = dot + b_wv[gn - 2048];
      else if (gn < 2465) {
        const float vv = dot + b_ig[gn - 2304];
        gate_buf[b * C_ + (gn - 2304)] = 1.f / (1.f + expf(-vv));
      } else {
        const float vv = dot + b_wg[0];
        wg_buf[b] = 1.f / (1.f + expf(-vv));
      }
    }
  }
}

// ---------------------------------------------------------------------------
// Kernel B: per-batch state math. Produces vm_new rows, sorted winner map
// (last-wins scatter), fwd/bwd top-16 positions, lum position.
// ---------------------------------------------------------------------------
__global__ __launch_bounds__(256) void state_kernel(
    const float* __restrict__ rws, const float* __restrict__ wws,
    const float* __restrict__ usage, const float* __restrict__ prec,
    const float* __restrict__ link, const float* __restrict__ rev_link,
    const float* __restrict__ vism, const int* __restrict__ rp,
    const int* __restrict__ lum, const float* __restrict__ wv_buf,
    const float* __restrict__ gate_buf, const float* __restrict__ wg_buf,
    float* __restrict__ vm_new, int* __restrict__ positions,
    int* __restrict__ win_pos, int* __restrict__ win_row, int* __restrict__ win_n)
{
  const int b = blockIdx.x, tid = threadIdx.x;
  __shared__ int   rp_l[C_];
  __shared__ float relu_l[C_], imin_l[C_], wwv_l[C_];
  __shared__ int   winflag[C_];
  __shared__ float fwd_l[TKL_], bwd_l[TKL_], tww_l[TKL_], trw_l[TKL_];
  __shared__ float redf[4];
  __shared__ int   redi[4];

  float rwv = 0.f, relu = 0.f;
  if (tid < C_) {
    const int p = rp[b * C_ + tid];
    rp_l[tid] = p;
    rwv      = rws[(size_t)b * M_ + p] + 1.0f;
    relu     = usage[(size_t)b * M_ + p];
    relu_l[tid] = relu;
  }
  __syncthreads();

  // min(rel_usage) over 161
  float mval = (tid < C_) ? relu : FLT_MAX;
  #pragma unroll
  for (int m = 1; m < 64; m <<= 1) mval = fminf(mval, __shfl_xor(mval, m));
  if ((tid & 63) == 0) redf[tid >> 6] = mval;
  __syncthreads();
  const float umin = fminf(fminf(redf[0], redf[1]), fminf(redf[2], redf[3]));

  if (tid < C_) {
    const float im = (relu == umin) ? 1.f : 0.f;
    imin_l[tid] = im;
    const float g  = gate_buf[b * C_ + tid];
    const float wg = wg_buf[b];
    wwv_l[tid] = wg * (g * rwv + (1.f - g) * im);
  }
  __syncthreads();

  // winner = last occurrence of each position (last-write-wins scatter)
  if (tid < C_) {
    const int p = rp_l[tid];
    int wf = 1;
    for (int c2 = tid + 1; c2 < C_; ++c2)
      if (rp_l[c2] == p) { wf = 0; break; }
    winflag[tid] = wf;
  }
  __syncthreads();

  // rank winners by position -> sorted winner map
  if (tid < C_ && winflag[tid]) {
    const int p = rp_l[tid];
    int rk = 0;
    for (int c2 = 0; c2 < C_; ++c2)
      if (winflag[c2] && rp_l[c2] < p) rk++;
    win_pos[b * C_ + rk] = p;
    win_row[b * C_ + rk] = tid;
  }
  int cnt = (tid < C_) ? winflag[tid] : 0;
  #pragma unroll
  for (int m = 1; m < 64; m <<= 1) cnt += __shfl_xor(cnt, m);
  if ((tid & 63) == 0) redi[tid >> 6] = cnt;
  __syncthreads();
  if (tid == 0) win_n[b] = redi[0] + redi[1] + redi[2] + redi[3];

  // vm_new rows: vism*(1-Imin) + wwv*write_vector
  for (int idx = tid; idx < C_ * WC; idx += 256) {
    const int c = idx >> 8, w = idx & 255;
    vm_new[((size_t)b * C_ + c) * WC + w] =
        vism[((size_t)b * C_ + c) * WC + w] * (1.f - imin_l[c]) +
        wwv_l[c] * wv_buf[b * WC + w];
  }

  // trp-derived quantities
  if (tid < TKL_) {
    const int tp = rp_l[129 + tid];
    int cl = -1;
    for (int c = C_ - 1; c >= 0; --c) if (rp_l[c] == tp) { cl = c; break; }
    tww_l[tid] = wwv_l[cl];                    // always found (tp in rp)
    trw_l[tid] = rws[(size_t)b * M_ + tp];
  }
  __syncthreads();

  if (tid < TKL_) {
    const int m = tid;
    // wws_new at row m (m < 32)
    int cl = -1;
    for (int c = C_ - 1; c >= 0; --c) if (rp_l[c] == m) { cl = c; break; }
    const float wwm = (cl >= 0) ? wwv_l[cl] : wws[(size_t)b * M_ + m];
    const float ld = (1.f - wwm) * link[((size_t)b * M_ + m) * TKL_ + m] +
                     wwm * prec[b * TKL_ + m];
    // prec_dense at row m: last k in trp with trp[k]==m
    int ck = -1;
    for (int c = C_ - 1; c >= 129; --c) if (rp_l[c] == m) { ck = c; break; }
    const float pd = (ck >= 0) ? prec[b * TKL_ + (ck - 129)] : 0.f;
    const float rd = (1.f - tww_l[m]) * rev_link[((size_t)b * M_ + m) * TKL_ + m] +
                     tww_l[m] * pd;
    fwd_l[m] = ld * trw_l[m];
    bwd_l[m] = rd * trw_l[m];
  }
  __syncthreads();

  // top-16 of fwd/bwd scores (nonzero only at m<32; zeros at 32.. fill rest,
  // ties broken by lower index — JAX top_k semantics). Rank over 48 candidates.
  const int lum0 = lum[0];
  if (tid < 48) {
    const float v = (tid < TKL_) ? fwd_l[tid] : 0.f;
    int rk = 0;
    for (int j = 0; j < 48; ++j) {
      const float vj = (j < TKL_) ? fwd_l[j] : 0.f;
      if (vj > v || (vj == v && j < tid)) rk++;
    }
    if (rk < 16) positions[b * C_ + 128 + rk] = min(tid, lum0);
  } else if (tid >= 64 && tid < 112) {
    const int t2 = tid - 64;
    const float v = (t2 < TKL_) ? bwd_l[t2] : 0.f;
    int rk = 0;
    for (int j = 0; j < 48; ++j) {
      const float vj = (j < TKL_) ? bwd_l[j] : 0.f;
      if (vj > v || (vj == v && j < t2)) rk++;
    }
    if (rk < 16) positions[b * C_ + 144 + rk] = min(t2, lum0);
  }
  if (tid == 128) positions[b * C_ + 160] = min(max(lum[b], 0), lum0);
}

// ---------------------------------------------------------------------------
// Recursive-halving reduce-scatter step: 64 partials/lane -> 1 sum/lane.
// After all 6 steps lane L holds the full sum of logical value L.
// ---------------------------------------------------------------------------
template <int K>
__device__ __forceinline__ void reduce_step64(float* A, int lane)
{
  const int mk = 1 << K;
  const bool hi = (lane & mk) != 0;
  #pragma unroll
  for (int t = 0; t < (32 >> K); ++t) {
    const float a0 = A[2 * t], a1 = A[2 * t + 1];
    const float csel = hi ? a0 : a1;  // the value I give away
    const float own  = hi ? a1 : a0;  // the value I keep
    A[t] = own + __shfl_xor(csel, mk);
  }
}

// ---------------------------------------------------------------------------
// Kernel C: scores[b][r][m] = rq[b][r] . memory[b][m]   (the 512 MB pass)
// Wave handles 16 rows (2 halves of 8); 64 partials/lane; reduce-scatter.
// Results staged through XOR-swizzled LDS so the final stores are 256 B
// coalesced row-major (avoids 8x32B scatter per wave-store -> 2x write amp).
// ---------------------------------------------------------------------------
__global__ __launch_bounds__(256) void scores_kernel(
    const float* __restrict__ mem, const float* __restrict__ rq_buf,
    float* __restrict__ scores)
{
  const int b    = blockIdx.y;
  const int tid  = threadIdx.x;
  const int lane = tid & 63;
  const int wave = tid >> 6;
  const int mblk = blockIdx.x * 64;
  const int mbase = mblk + wave * 16;
  __shared__ float st[8][64];   // [r][m_local], col XOR-swizzled by r<<3

  float4 rq4[8];
  #pragma unroll
  for (int r = 0; r < 8; ++r)
    rq4[r] = *(const float4*)(rq_buf + ((size_t)(b * 8 + r)) * WC + lane * 4);

  #pragma unroll
  for (int half = 0; half < 2; ++half) {
    const int m0 = mbase + half * 8;
    float A[64];
    #pragma unroll
    for (int i = 0; i < 64; ++i) A[i] = 0.f;

    #pragma unroll
    for (int row = 0; row < 8; ++row) {
      const float4 v = *(const float4*)(
          mem + ((size_t)b * M_ + m0 + row) * WC + lane * 4);
      #pragma unroll
      for (int r = 0; r < 8; ++r) {
        A[row * 8 + r] += v.x * rq4[r].x + v.y * rq4[r].y +
                          v.z * rq4[r].z + v.w * rq4[r].w;
      }
    }
    reduce_step64<0>(A, lane);
    reduce_step64<1>(A, lane);
    reduce_step64<2>(A, lane);
    reduce_step64<3>(A, lane);
    reduce_step64<4>(A, lane);
    reduce_step64<5>(A, lane);
    // lane L holds (r = L&7, row = L>>3); stage to LDS (swizzled, 2-way max)
    const int r  = lane & 7;
    const int ml = wave * 16 + half * 8 + (lane >> 3);
    st[r][ml ^ (r << 3)] = A[0];
  }
  __syncthreads();

  // coalesced write-out: 512 values, 2 per thread, 256 B per wave-store
  #pragma unroll
  for (int h = 0; h < 2; ++h) {
    const int r = h * 4 + wave;
    scores[((size_t)b * 8 + r) * M_ + mblk + lane] = st[r][lane ^ (r << 3)];
  }
}

// ---------------------------------------------------------------------------
// Kernel D: fixup — overwrite scores at winner rows with rq . vm_new
// ---------------------------------------------------------------------------
__global__ __launch_bounds__(256) void fixup_kernel(
    const float* __restrict__ rq_buf, const float* __restrict__ vm_new,
    const int* __restrict__ win_pos, const int* __restrict__ win_row,
    const int* __restrict__ win_n, float* __restrict__ scores)
{
  const int b    = blockIdx.x;
  const int lane = threadIdx.x & 63;
  const int wave = threadIdx.x >> 6;
  const int nw   = win_n[b];

  float4 rq4[8];
  #pragma unroll
  for (int r = 0; r < 8; ++r)
    rq4[r] = *(const float4*)(rq_buf + ((size_t)(b * 8 + r)) * WC + lane * 4);

  for (int j = wave; j < nw; j += 4) {
    const int p = win_pos[b * C_ + j];
    const int c = win_row[b * C_ + j];
    const float4 v = *(const float4*)(
        vm_new + ((size_t)b * C_ + c) * WC + lane * 4);
    float A[8];
    #pragma unroll
    for (int r = 0; r < 8; ++r)
      A[r] = v.x * rq4[r].x + v.y * rq4[r].y + v.z * rq4[r].z + v.w * rq4[r].w;

    // halve over r-bits (lane bits 0..2), then plain-add over bits 3..5
    #pragma unroll
    for (int k = 0; k < 3; ++k) {
      const int mk = 1 << k;
      const bool hi = (lane & mk) != 0;
      #pragma unroll
      for (int t = 0; t < (4 >> k); ++t) {
        const float a0 = A[2 * t], a1 = A[2 * t + 1];
        const float csel = hi ? a0 : a1;
        const float own  = hi ? a1 : a0;
        A[t] = own + __shfl_xor(csel, mk);
      }
    }
    A[0] += __shfl_xor(A[0], 8);
    A[0] += __shfl_xor(A[0], 16);
    A[0] += __shfl_xor(A[0], 32);
    if (lane < 8)
      scores[((size_t)b * 8 + lane) * M_ + p] = A[0];
  }
}

// ---------------------------------------------------------------------------
// Kernel E: top-16 per (b,r) over M=16384 scores, JAX tie semantics
// (desc value, asc index). 4 waves x 4096 elems; per-lane sorted top-16,
// pop-merge within wave, then across waves.
// ---------------------------------------------------------------------------
__global__ __launch_bounds__(256) void topk_kernel(
    const float* __restrict__ scores, const int* __restrict__ lum,
    int* __restrict__ positions)
{
  const int br   = blockIdx.x;        // b*8 + r
  const int b    = br >> 3, r = br & 7;
  const int lane = threadIdx.x & 63;
  const int wave = threadIdx.x >> 6;
  __shared__ float lv[64];
  __shared__ int   li[64];

  const float* row = scores + (size_t)br * M_;
  float val[16];
  int   idx[16];
  #pragma unroll
  for (int t = 0; t < 16; ++t) { val[t] = -FLT_MAX; idx[t] = 0x7FFFFFFF; }

  const int base = wave * 4096;
  for (int i = 0; i < 64; ++i) {
    const int m = base + i * 64 + lane;
    const float v = row[m];
    if (v > val[15]) {
      #pragma unroll
      for (int t = 15; t >= 1; --t) {
        const bool sh  = val[t - 1] < v;
        const bool put = (!sh) && (val[t] < v);
        if (sh)      { val[t] = val[t - 1]; idx[t] = idx[t - 1]; }
        else if (put){ val[t] = v;          idx[t] = m; }
      }
      if (val[0] < v) { val[0] = v; idx[0] = m; }
    }
  }

  // wave merge: 16 rounds of argmax-with-claim over lane heads
  float resv = -FLT_MAX; int resi = 0;
  for (int t = 0; t < 16; ++t) {
    float wv = val[0]; int wi = idx[0];
    #pragma unroll
    for (int m = 1; m < 64; m <<= 1) {
      const float ov = __shfl_xor(wv, m);
      const int   oi = __shfl_xor(wi, m);
      if (ov > wv || (ov == wv && oi < wi)) { wv = ov; wi = oi; }
    }
    if (val[0] == wv && idx[0] == wi) {
      #pragma unroll
      for (int k = 0; k < 15; ++k) { val[k] = val[k + 1]; idx[k] = idx[k + 1]; }
      val[15] = -FLT_MAX; idx[15] = 0x7FFFFFFF;
    }
    if (lane == t) { resv = wv; resi = wi; }
  }
  if (lane < 16) { lv[wave * 16 + lane] = resv; li[wave * 16 + lane] = resi; }
  __syncthreads();

  if (wave == 0) {
    float cv = lv[lane]; int ci = li[lane];
    const int lum0 = lum[0];
    float rv2 = -FLT_MAX; int ri2 = 0;
    for (int t = 0; t < 16; ++t) {
      float wv = cv; int wi = ci;
      #pragma unroll
      for (int m = 1; m < 64; m <<= 1) {
        const float ov = __shfl_xor(wv, m);
        const int   oi = __shfl_xor(wi, m);
        if (ov > wv || (ov == wv && oi < wi)) { wv = ov; wi = oi; }
      }
      if (cv == wv && ci == wi) cv = -FLT_MAX;   // claim (idx unique)
      if (lane == t) { rv2 = wv; ri2 = wi; }
    }
    (void)rv2;
    if (lane < 16)
      positions[b * C_ + r * 16 + lane] = min(max(ri2, 0), lum0);
  }
}

// ---------------------------------------------------------------------------
// Kernel F: gather vis rows (with winner override), cosine, softmax, readout
// One block per (b,r).
// ---------------------------------------------------------------------------
__global__ __launch_bounds__(256) void out_kernel(
    const float* __restrict__ mem, const float* __restrict__ rq_buf,
    const float* __restrict__ vm_new, const int* __restrict__ positions,
    const int* __restrict__ win_pos, const int* __restrict__ win_row,
    const int* __restrict__ win_n, float* __restrict__ out)
{
  const int br = blockIdx.x, b = br >> 3;
  const int tid = threadIdx.x, lane = tid & 63, wave = tid >> 6;
  __shared__ const float* src_l[C_];
  __shared__ float rq_l[WC];
  __shared__ float dot_l[C_], an_l[C_], w_l[C_];
  __shared__ float redf[4];

  const float q = rq_buf[(size_t)br * WC + tid];
  rq_l[tid] = q;
  float p2 = q * q;
  #pragma unroll
  for (int m = 1; m < 64; m <<= 1) p2 += __shfl_xor(p2, m);
  if ((tid & 63) == 0) redf[wave] = p2;

  if (tid < C_) {
    const int p  = positions[b * C_ + tid];
    const int nw = win_n[b];
    int lo = 0, hi = nw - 1, f = -1;
    while (lo <= hi) {
      const int md = (lo + hi) >> 1;
      const int wp = win_pos[b * C_ + md];
      if (wp == p) { f = md; break; }
      if (wp < p) lo = md + 1; else hi = md - 1;
    }
    src_l[tid] = (f >= 0)
        ? (vm_new + ((size_t)b * C_ + win_row[b * C_ + f]) * WC)
        : (mem + ((size_t)b * M_ + p) * WC);
  }
  __syncthreads();
  const float bn = sqrtf(redf[0] + redf[1] + redf[2] + redf[3]) + 1e-6f;

  const float4 rq4 = *(const float4*)(rq_l + lane * 4);
  for (int c = wave; c < C_; c += 4) {
    const float4 v = *(const float4*)(src_l[c] + lane * 4);
    float pd = v.x * rq4.x + v.y * rq4.y + v.z * rq4.z + v.w * rq4.w;
    float pn = v.x * v.x + v.y * v.y + v.z * v.z + v.w * v.w;
    #pragma unroll
    for (int m = 1; m < 64; m <<= 1) {
      pd += __shfl_xor(pd, m);
      pn += __shfl_xor(pn, m);
    }
    if (lane == 0) { dot_l[c] = pd; an_l[c] = sqrtf(pn) + 1e-6f; }
  }
  __syncthreads();

  float cs = -FLT_MAX;
  if (tid < C_) cs = dot_l[tid] / (256.f * bn * an_l[tid] + 1e-6f);
  // block max
  float mv = cs;
  #pragma unroll
  for (int m = 1; m < 64; m <<= 1) mv = fmaxf(mv, __shfl_xor(mv, m));
  if ((tid & 63) == 0) redf[wave] = mv;
  __syncthreads();
  const float mx = fmaxf(fmaxf(redf[0], redf[1]), fmaxf(redf[2], redf[3]));
  float ex = 0.f;
  if (tid < C_) { ex = expf(cs - mx); w_l[tid] = ex; }
  __syncthreads();
  float sv = ex;
  #pragma unroll
  for (int m = 1; m < 64; m <<= 1) sv += __shfl_xor(sv, m);
  if ((tid & 63) == 0) redf[wave] = sv;
  __syncthreads();
  const float ssum = redf[0] + redf[1] + redf[2] + redf[3];

  float acc = 0.f;
  #pragma unroll 4
  for (int c = 0; c < C_; ++c) acc += w_l[c] * src_l[c][tid];
  out[(size_t)br * WC + tid] = acc / ssum;
}

// ---------------------------------------------------------------------------
extern "C" void kernel_launch(void* const* d_in, const int* in_sizes, int n_in,
                              void* d_out, int out_size, void* d_ws, size_t ws_size,
                              hipStream_t stream)
{
  (void)in_sizes; (void)n_in; (void)out_size; (void)ws_size;
  const float* x     = (const float*)d_in[0];
  const float* mem   = (const float*)d_in[1];
  const float* vism  = (const float*)d_in[2];
  const float* link  = (const float*)d_in[3];
  const float* rlink = (const float*)d_in[4];
  const float* prec  = (const float*)d_in[5];
  const float* rws   = (const float*)d_in[6];
  const float* wws   = (const float*)d_in[7];
  const float* usage = (const float*)d_in[8];
  const float* W_rq  = (const float*)d_in[9];
  const float* b_rq  = (const float*)d_in[10];
  const float* W_wv  = (const float*)d_in[11];
  const float* b_wv  = (const float*)d_in[12];
  const float* W_ig  = (const float*)d_in[13];
  const float* b_ig  = (const float*)d_in[14];
  const float* W_wg  = (const float*)d_in[15];
  const float* b_wg  = (const float*)d_in[16];
  const int*   rp    = (const int*)d_in[17];
  const int*   lum   = (const int*)d_in[18];
  float* out = (float*)d_out;

  char* ws = (char*)d_ws;
  size_t off = 0;
  auto alloc = [&](size_t bytes) {
    void* p = ws + off;
    off += (bytes + 255) & ~(size_t)255;
    return p;
  };
  float* scores   = (float*)alloc((size_t)B_ * R_ * M_ * 4);   // 16 MB
  float* vm_new   = (float*)alloc((size_t)B_ * C_ * WC * 4);   // 5.3 MB
  float* rq_buf   = (float*)alloc((size_t)B_ * R_ * WC * 4);
  float* wv_buf   = (float*)alloc((size_t)B_ * WC * 4);
  float* gate_buf = (float*)alloc((size_t)B_ * C_ * 4);
  float* wg_buf   = (float*)alloc((size_t)B_ * 4);
  int*   positions= (int*)alloc((size_t)B_ * C_ * 4);
  int*   win_pos  = (int*)alloc((size_t)B_ * C_ * 4);
  int*   win_row  = (int*)alloc((size_t)B_ * C_ * 4);
  int*   win_n    = (int*)alloc((size_t)B_ * 4);

  gemm_small<<<dim3(155), dim3(256), 0, stream>>>(
      x, W_rq, b_rq, W_wv, b_wv, W_ig, b_ig, W_wg, b_wg,
      rq_buf, wv_buf, gate_buf, wg_buf);

  state_kernel<<<dim3(B_), dim3(256), 0, stream>>>(
      rws, wws, usage, prec, link, rlink, vism, rp, lum,
      wv_buf, gate_buf, wg_buf, vm_new, positions, win_pos, win_row, win_n);

  scores_kernel<<<dim3(M_ / 64, B_), dim3(256), 0, stream>>>(
      mem, rq_buf, scores);

  fixup_kernel<<<dim3(B_), dim3(256), 0, stream>>>(
      rq_buf, vm_new, win_pos, win_row, win_n, scores);

  topk_kernel<<<dim3(B_ * R_), dim3(256), 0, stream>>>(
      scores, lum, positions);

  out_kernel<<<dim3(B_ * R_), dim3(256), 0, stream>>>(
      mem, rq_buf, vm_new, positions, win_pos, win_row, win_n, out);
}